// Round 5
// baseline (775.394 us; speedup 1.0000x reference)
//
#include <hip/hip_runtime.h>
#include <hip/hip_bf16.h>

typedef unsigned short u16;
typedef unsigned int u32;
typedef __attribute__((ext_vector_type(8))) short bf16x8;
typedef __attribute__((ext_vector_type(4))) float f32x4;
typedef __attribute__((ext_vector_type(4))) u16 u16x4;
typedef __attribute__((ext_vector_type(4))) u32 u32x4;

#define NPATCH 81920
#define NBATCH 4
#define NROWS (NBATCH * NPATCH)   // 327680
#define HID 128
#define NC32 (NROWS / 32)         // 10240 chunks of 32 rows
#define GRID 512                  // 512 blocks x 4 waves = 2048 waves -> 5 chunks/wave

__device__ __forceinline__ u16 f2bf(float x) {
  union { __hip_bfloat16 b; u16 u; } c; c.b = __float2bfloat16(x); return c.u;
}
__device__ __forceinline__ float bf2f(u16 h) {
  union { __hip_bfloat16 b; u16 u; } c; c.u = h; return __bfloat162float(c.b);
}

union B8 { u32x4 u; bf16x8 b; };

// ---------------- weight prep (layouts identical to round 3/4, verified) ----------------
// wf  : [part(2)][kg(16)][n(128)][j(8)]  (k' = kg*8+j = s*32+d -> W1 row d*4+s)
// w2f : [part(2)][kt(4)][lg(4)][o(16)][j(8)]  -> serves as W2T A-frag AND W2 B-frag
__global__ void prep_w(const float* __restrict__ W1, const float* __restrict__ W2,
                       u16* __restrict__ wf, u16* __restrict__ w2f) {
  int t = blockIdx.x * 256 + threadIdx.x;
  if (t < 128 * 128) {
    int kp = t >> 7, n = t & 127;
    int s = kp >> 5, d = kp & 31;
    float v = W1[(d * 4 + s) * HID + n];
    u16 h = f2bf(v);
    u16 l = f2bf(v - bf2f(h));
    int kg = kp >> 3, j = kp & 7;
    int o = (kg * 128 + n) * 8 + j;
    wf[o] = h;
    wf[16384 + o] = l;
  } else if (t < 128 * 128 + 2048) {
    int u = t - 128 * 128;            // u = k*16 + o
    int k = u >> 4, o = u & 15;
    float v = W2[k * 16 + o];
    u16 h = f2bf(v);
    u16 l = f2bf(v - bf2f(h));
    int kt = k >> 5, lg = (k >> 3) & 3, j = k & 7;
    int idx = ((kt * 4 + lg) * 16 + o) * 8 + j;
    w2f[idx] = h;
    w2f[2048 + idx] = l;
  }
}

// z split. MERGED: 128B rows [d0-15 hi|d0-15 lo|d16-31 hi|d16-31 lo] -> BOTH A0,B0.
// else: A0 = dynamic 64B rows [hi16|lo16], B0 = static 64B rows [hi16|lo16].
template<int MERGED>
__global__ void prep_z(const float* __restrict__ z, u16* __restrict__ A0, u16* __restrict__ B0) {
  int t = blockIdx.x * 256 + threadIdx.x;
  if (t >= NROWS * 8) return;
  size_t row = (size_t)(t >> 3);
  int q = t & 7;
  float4 v = *(const float4*)&z[row * 32 + q * 4];
  u16 h0 = f2bf(v.x), h1 = f2bf(v.y), h2 = f2bf(v.z), h3 = f2bf(v.w);
  u16 l0 = f2bf(v.x - bf2f(h0)), l1 = f2bf(v.y - bf2f(h1));
  u16 l2 = f2bf(v.z - bf2f(h2)), l3 = f2bf(v.w - bf2f(h3));
  u16x4 hh = {h0, h1, h2, h3};
  u16x4 ll = {l0, l1, l2, l3};
  int dd = (q & 3) * 4;
  if (MERGED) {
    int reg = (q < 4) ? 0 : 32;
    *(u16x4*)&A0[row * 64 + reg + dd] = hh;
    *(u16x4*)&A0[row * 64 + reg + 16 + dd] = ll;
    *(u16x4*)&B0[row * 64 + reg + dd] = hh;
    *(u16x4*)&B0[row * 64 + reg + 16 + dd] = ll;
  } else {
    u16* buf = (q < 4) ? A0 : B0;
    *(u16x4*)&buf[row * 32 + dd] = hh;
    *(u16x4*)&buf[row * 32 + 16 + dd] = ll;
  }
}

// ---------------- one solver step: per-wave independent, zero in-loop barriers ----------------
template<int FIRST, int LAST, int MERGED>
__global__ __launch_bounds__(256, 2) void step_kernel(
    const u16* __restrict__ Zin, u16* __restrict__ Zout,
    const u16* __restrict__ Sst,
    const float* __restrict__ zold, float* __restrict__ zf,
    const int* __restrict__ nl, const float* __restrict__ b1,
    const float* __restrict__ b2, const u16* __restrict__ wf,
    const u16* __restrict__ w2f) {
  __shared__ __align__(16) u16 W1L[32768];   // 64 KB: W1 hi (16384) + lo (16384), frag order

  const int tid = threadIdx.x;
  const int lane = tid & 63;
  const int w = tid >> 6;
  const int li = lane & 15;
  const int lg = lane >> 4;

  // stage W1 fragments into LDS (linear, conflict-free: lanes stride 16B)
  #pragma unroll
  for (int i = 0; i < 16; ++i)
    *(bf16x8*)&W1L[i * 2048 + tid * 8] = *(const bf16x8*)&wf[i * 2048 + tid * 8];
  __syncthreads();   // the ONLY block-wide barrier

  const int wid = blockIdx.x * 4 + w;
  const int soff = lg * 8 + ((lg >> 1) << 4);          // merged hi-slice elem offset
  const int a0 = (li + ((lg & 1) << 5)) << 2;          // bpermute byte addr, src lg = 2*(lg&1)
  const int a1 = a0 + 64;                              // src lg = 2*(lg&1)+1
  const f32x4 b2v = *(const f32x4*)&b2[lg * 4];

  // ---- per-chunk load helpers ----
  int nlv[3][2], nlv2[3][2];
  bf16x8 ah[4][2], al[4][2];

  #define LOADNL(CC, DST) do {                                              \
    int r0_ = (CC) * 32;                                                    \
    int b_ = r0_ / NPATCH;                                                  \
    int pb_ = r0_ - b_ * NPATCH;                                            \
    _Pragma("unroll")                                                       \
    for (int mt_ = 0; mt_ < 2; ++mt_) {                                     \
      int p_ = pb_ + mt_ * 16 + li;                                         \
      DST[0][mt_] = nl[p_ * 3 + 0];                                         \
      DST[1][mt_] = nl[p_ * 3 + 1];                                         \
      DST[2][mt_] = nl[p_ * 3 + 2];                                         \
    }                                                                       \
  } while (0)

  #define LOADA(CC, NV) do {                                                \
    int r0_ = (CC) * 32;                                                    \
    int b_ = r0_ / NPATCH;                                                  \
    int pb_ = r0_ - b_ * NPATCH;                                            \
    size_t rb_ = (size_t)b_ * NPATCH;                                       \
    _Pragma("unroll")                                                       \
    for (int mt_ = 0; mt_ < 2; ++mt_) {                                     \
      int self_ = pb_ + mt_ * 16 + li;                                      \
      _Pragma("unroll")                                                     \
      for (int kt_ = 0; kt_ < 4; ++kt_) {                                   \
        int ps_ = (kt_ == 0) ? self_ : NV[kt_ - 1][mt_];                    \
        if (MERGED) {                                                       \
          const u16* p_ = Zin + (rb_ + (size_t)ps_) * 64 + soff;            \
          ah[kt_][mt_] = *(const bf16x8*)p_;                                \
          al[kt_][mt_] = *(const bf16x8*)(p_ + 16);                         \
        } else {                                                            \
          const u16* base_ = (lg < 2) ? (Zin + (rb_ + (size_t)ps_) * 32)    \
                                      : (Sst + (rb_ + (size_t)ps_) * 32);   \
          const u16* p_ = base_ + (lg & 1) * 8;                             \
          ah[kt_][mt_] = *(const bf16x8*)p_;                                \
          al[kt_][mt_] = *(const bf16x8*)(p_ + 16);                         \
        }                                                                   \
      }                                                                     \
    }                                                                       \
  } while (0)

  // ---- prologue ----
  if (wid >= NC32) return;
  LOADNL(wid, nlv);
  LOADA(wid, nlv);
  {
    int c1 = wid + GRID * 4; if (c1 > NC32 - 1) c1 = NC32 - 1;
    LOADNL(c1, nlv2);
  }

  for (int c = wid; c < NC32; c += GRID * 4) {
    const int cn = c + GRID * 4;
    const bool hn = cn < NC32;

    // prefetch zi (epilogue read) for current chunk
    f32x4 zi[2], zs[2];
    #pragma unroll
    for (int mt = 0; mt < 2; ++mt) {
      int rowg = c * 32 + mt * 16 + li;
      zi[mt] = FIRST ? *(const f32x4*)&zold[(size_t)rowg * 32 + lg * 4]
                     : *(const f32x4*)&zf[(size_t)rowg * 32 + lg * 4];
      if (LAST) zs[mt] = *(const f32x4*)&zold[(size_t)rowg * 32 + 16 + lg * 4];
    }

    // ---- GEMM1 (transposed): D[n][m] = W1T @ A^T, bf16x3 split ----
    f32x4 acc[8][2];
    #pragma unroll
    for (int nt = 0; nt < 8; ++nt)
      #pragma unroll
      for (int mt = 0; mt < 2; ++mt)
        acc[nt][mt] = (f32x4){0.f, 0.f, 0.f, 0.f};

    #pragma unroll
    for (int kt = 0; kt < 4; ++kt) {
      #pragma unroll
      for (int nt = 0; nt < 8; ++nt) {
        int woff = ((kt * 4 + lg) * 128 + nt * 16 + li) * 8;
        bf16x8 whf = *(const bf16x8*)&W1L[woff];
        bf16x8 wlf = *(const bf16x8*)&W1L[16384 + woff];
        #pragma unroll
        for (int mt = 0; mt < 2; ++mt) {
          acc[nt][mt] = __builtin_amdgcn_mfma_f32_16x16x32_bf16(whf, ah[kt][mt], acc[nt][mt], 0, 0, 0);
          acc[nt][mt] = __builtin_amdgcn_mfma_f32_16x16x32_bf16(whf, al[kt][mt], acc[nt][mt], 0, 0, 0);
          acc[nt][mt] = __builtin_amdgcn_mfma_f32_16x16x32_bf16(wlf, ah[kt][mt], acc[nt][mt], 0, 0, 0);
        }
      }
    }

    // ---- bias + tanh + bf16 hi/lo pack (all in registers) ----
    u32 H01[2][8], H23[2][8], L01[2][8], L23[2][8];
    #pragma unroll
    for (int nt = 0; nt < 8; ++nt) {
      f32x4 bb = *(const f32x4*)&b1[nt * 16 + lg * 4];
      #pragma unroll
      for (int mt = 0; mt < 2; ++mt) {
        u16 hu[4]; float lo[4];
        #pragma unroll
        for (int r = 0; r < 4; ++r) {
          float x = acc[nt][mt][r] + bb[r];
          float e = __expf(2.0f * x);
          float t = 1.0f - 2.0f * __builtin_amdgcn_rcpf(e + 1.0f);
          u16 h = f2bf(t);
          hu[r] = h;
          lo[r] = t - bf2f(h);
        }
        H01[mt][nt] = (u32)hu[0] | ((u32)hu[1] << 16);
        H23[mt][nt] = (u32)hu[2] | ((u32)hu[3] << 16);
        L01[mt][nt] = (u32)f2bf(lo[0]) | ((u32)f2bf(lo[1]) << 16);
        L23[mt][nt] = (u32)f2bf(lo[2]) | ((u32)f2bf(lo[3]) << 16);
      }
    }

    // issue next chunk's gathers now (latency hides under shuffle+GEMM2+epilogue)
    if (hn) LOADA(cn, nlv2);

    // W2T fragments (tiny, L1-hot)
    bf16x8 w2h[4], w2l[4];
    #pragma unroll
    for (int s = 0; s < 4; ++s) {
      int o = ((s * 4 + lg) * 16 + li) * 8;
      w2h[s] = *(const bf16x8*)&w2f[o];
      w2l[s] = *(const bf16x8*)&w2f[2048 + o];
    }

    // ---- in-register h redistribution (ds_bpermute) + GEMM2T: FT[o][m] = W2T @ hT ----
    const bool odd = (lg >= 2);
    f32x4 acc2[2];
    #pragma unroll
    for (int mt = 0; mt < 2; ++mt) {
      acc2[mt] = (f32x4){0.f, 0.f, 0.f, 0.f};
      #pragma unroll
      for (int s = 0; s < 4; ++s) {
        B8 hf, lf;
        u32 e0, e1;
        e0 = (u32)__builtin_amdgcn_ds_bpermute(a0, (int)H01[mt][2 * s]);
        e1 = (u32)__builtin_amdgcn_ds_bpermute(a0, (int)H01[mt][2 * s + 1]);
        hf.u[0] = odd ? e1 : e0;
        e0 = (u32)__builtin_amdgcn_ds_bpermute(a0, (int)H23[mt][2 * s]);
        e1 = (u32)__builtin_amdgcn_ds_bpermute(a0, (int)H23[mt][2 * s + 1]);
        hf.u[1] = odd ? e1 : e0;
        e0 = (u32)__builtin_amdgcn_ds_bpermute(a1, (int)H01[mt][2 * s]);
        e1 = (u32)__builtin_amdgcn_ds_bpermute(a1, (int)H01[mt][2 * s + 1]);
        hf.u[2] = odd ? e1 : e0;
        e0 = (u32)__builtin_amdgcn_ds_bpermute(a1, (int)H23[mt][2 * s]);
        e1 = (u32)__builtin_amdgcn_ds_bpermute(a1, (int)H23[mt][2 * s + 1]);
        hf.u[3] = odd ? e1 : e0;

        e0 = (u32)__builtin_amdgcn_ds_bpermute(a0, (int)L01[mt][2 * s]);
        e1 = (u32)__builtin_amdgcn_ds_bpermute(a0, (int)L01[mt][2 * s + 1]);
        lf.u[0] = odd ? e1 : e0;
        e0 = (u32)__builtin_amdgcn_ds_bpermute(a0, (int)L23[mt][2 * s]);
        e1 = (u32)__builtin_amdgcn_ds_bpermute(a0, (int)L23[mt][2 * s + 1]);
        lf.u[1] = odd ? e1 : e0;
        e0 = (u32)__builtin_amdgcn_ds_bpermute(a1, (int)L01[mt][2 * s]);
        e1 = (u32)__builtin_amdgcn_ds_bpermute(a1, (int)L01[mt][2 * s + 1]);
        lf.u[2] = odd ? e1 : e0;
        e0 = (u32)__builtin_amdgcn_ds_bpermute(a1, (int)L23[mt][2 * s]);
        e1 = (u32)__builtin_amdgcn_ds_bpermute(a1, (int)L23[mt][2 * s + 1]);
        lf.u[3] = odd ? e1 : e0;

        acc2[mt] = __builtin_amdgcn_mfma_f32_16x16x32_bf16(w2h[s], hf.b, acc2[mt], 0, 0, 0);
        acc2[mt] = __builtin_amdgcn_mfma_f32_16x16x32_bf16(w2h[s], lf.b, acc2[mt], 0, 0, 0);
        acc2[mt] = __builtin_amdgcn_mfma_f32_16x16x32_bf16(w2l[s], hf.b, acc2[mt], 0, 0, 0);
      }
    }

    // ---- epilogue: z_out[:, :16] = z_in[:, :16] + F ----
    #pragma unroll
    for (int mt = 0; mt < 2; ++mt) {
      int rowg = c * 32 + mt * 16 + li;
      f32x4 v;
      #pragma unroll
      for (int r = 0; r < 4; ++r) v[r] = zi[mt][r] + acc2[mt][r] + b2v[r];
      *(f32x4*)&zf[(size_t)rowg * 32 + lg * 4] = v;
      if (LAST) {
        *(f32x4*)&zf[(size_t)rowg * 32 + 16 + lg * 4] = zs[mt];
      } else {
        u16x4 hv, lv;
        #pragma unroll
        for (int r = 0; r < 4; ++r) {
          u16 h = f2bf(v[r]);
          hv[r] = h;
          lv[r] = f2bf(v[r] - bf2f(h));
        }
        if (MERGED) {
          *(u16x4*)&Zout[(size_t)rowg * 64 + lg * 4] = hv;
          *(u16x4*)&Zout[(size_t)rowg * 64 + 16 + lg * 4] = lv;
        } else {
          *(u16x4*)&Zout[(size_t)rowg * 32 + lg * 4] = hv;
          *(u16x4*)&Zout[(size_t)rowg * 32 + 16 + lg * 4] = lv;
        }
      }
    }

    // rotate nl prefetch
    #pragma unroll
    for (int k = 0; k < 3; ++k)
      #pragma unroll
      for (int mt = 0; mt < 2; ++mt)
        nlv[k][mt] = nlv2[k][mt];
    {
      int c2 = cn + GRID * 4; if (c2 > NC32 - 1) c2 = NC32 - 1;
      if (hn) LOADNL(c2, nlv2);
    }
  }
  #undef LOADA
  #undef LOADNL
}

extern "C" void kernel_launch(void* const* d_in, const int* in_sizes, int n_in,
                              void* d_out, int out_size, void* d_ws, size_t ws_size,
                              hipStream_t stream) {
  const float* z_old = (const float*)d_in[0];
  const int* nl = (const int*)d_in[1];
  const float* W1 = (const float*)d_in[2];
  const float* b1 = (const float*)d_in[3];
  const float* W2 = (const float*)d_in[4];
  const float* b2 = (const float*)d_in[5];
  float* out = (float*)d_out;

  const size_t wOff = 73728;
  const size_t DbM = (size_t)NROWS * 64 * sizeof(u16);   // 40 MB merged buffer
  const size_t DbS = (size_t)NROWS * 32 * sizeof(u16);   // 20 MB split buffer
  const size_t needM = wOff + 2 * DbM;                   // ~84 MB
  u16* wf = (u16*)d_ws;
  u16* w2f = wf + 32768;
  char* base = (char*)d_ws + wOff;

  prep_w<<<72, 256, 0, stream>>>(W1, W2, wf, w2f);

  if (ws_size >= needM) {
    u16* ZA = (u16*)base;
    u16* ZB = (u16*)(base + DbM);
    prep_z<1><<<(NROWS * 8) / 256, 256, 0, stream>>>(z_old, ZA, ZB);
    step_kernel<1, 0, 1><<<GRID, 256, 0, stream>>>(ZA, ZB, nullptr, z_old, out, nl, b1, b2, wf, w2f);
    step_kernel<0, 0, 1><<<GRID, 256, 0, stream>>>(ZB, ZA, nullptr, z_old, out, nl, b1, b2, wf, w2f);
    step_kernel<0, 0, 1><<<GRID, 256, 0, stream>>>(ZA, ZB, nullptr, z_old, out, nl, b1, b2, wf, w2f);
    step_kernel<0, 1, 1><<<GRID, 256, 0, stream>>>(ZB, ZA, nullptr, z_old, out, nl, b1, b2, wf, w2f);
  } else {
    u16* S  = (u16*)base;
    u16* DA = (u16*)(base + DbS);
    u16* DB = (u16*)(base + 2 * DbS);
    prep_z<0><<<(NROWS * 8) / 256, 256, 0, stream>>>(z_old, DA, S);
    step_kernel<1, 0, 0><<<GRID, 256, 0, stream>>>(DA, DB, S, z_old, out, nl, b1, b2, wf, w2f);
    step_kernel<0, 0, 0><<<GRID, 256, 0, stream>>>(DB, DA, S, z_old, out, nl, b1, b2, wf, w2f);
    step_kernel<0, 0, 0><<<GRID, 256, 0, stream>>>(DA, DB, S, z_old, out, nl, b1, b2, wf, w2f);
    step_kernel<0, 1, 0><<<GRID, 256, 0, stream>>>(DB, DA, S, z_old, out, nl, b1, b2, wf, w2f);
  }
}

// Round 6
// 689.154 us; speedup vs baseline: 1.1251x; 1.1251x over previous
//
#include <hip/hip_runtime.h>
#include <hip/hip_bf16.h>

typedef unsigned short u16;
typedef unsigned int u32;
typedef __attribute__((ext_vector_type(8))) short bf16x8;
typedef __attribute__((ext_vector_type(4))) float f32x4;
typedef __attribute__((ext_vector_type(4))) u16 u16x4;

#define NPATCH 81920
#define NBATCH 4
#define NROWS (NBATCH * NPATCH)   // 327680
#define HID 128
#define CHUNK 64
#define NCHUNK (NROWS / CHUNK)    // 5120
#define CPB (NPATCH / CHUNK)      // 1280
#define GRID 1280                 // 5 blocks/CU * 256 CUs; 4 chunks/block exactly

// ---------- conversion helpers (RNE) ----------
__device__ __forceinline__ u16 f2bf(float x) {
  union { __hip_bfloat16 b; u16 u; } c; c.b = __float2bfloat16(x); return c.u;
}
__device__ __forceinline__ float bf2f(u16 h) {
  union { __hip_bfloat16 b; u16 u; } c; c.u = h; return __bfloat162float(c.b);
}

// async global->LDS DMA, 16B/lane, dest = wave-uniform base + lane*16
#define GLD(g, l) __builtin_amdgcn_global_load_lds( \
    (const __attribute__((address_space(1))) void*)(g), \
    (__attribute__((address_space(3))) void*)(l), 16, 0, 0)
#define SBAR() __builtin_amdgcn_s_barrier()
#define SCHED0() __builtin_amdgcn_sched_barrier(0)

// ---------------- weight prep (layouts identical to rounds 3-5, verified) ----------------
// wf  : [part(2)][kg(16)][n(128)][j(8)]  (k' = kg*8+j = s*32+d -> W1 row d*4+s)
// w2f : [part(2)][kt(4)][lg(4)][o(16)][j(8)]
__global__ void prep_w(const float* __restrict__ W1, const float* __restrict__ W2,
                       u16* __restrict__ wf, u16* __restrict__ w2f) {
  int t = blockIdx.x * 256 + threadIdx.x;
  if (t < 128 * 128) {
    int kp = t >> 7, n = t & 127;
    int s = kp >> 5, d = kp & 31;
    float v = W1[(d * 4 + s) * HID + n];
    u16 h = f2bf(v);
    u16 l = f2bf(v - bf2f(h));
    int kg = kp >> 3, j = kp & 7;
    int o = (kg * 128 + n) * 8 + j;
    wf[o] = h;
    wf[16384 + o] = l;
  } else if (t < 128 * 128 + 2048) {
    int u = t - 128 * 128;            // u = k*16 + o
    int k = u >> 4, o = u & 15;
    float v = W2[k * 16 + o];
    u16 h = f2bf(v);
    u16 l = f2bf(v - bf2f(h));
    int kt = k >> 5, lg = (k >> 3) & 3, j = k & 7;
    int idx = ((kt * 4 + lg) * 16 + o) * 8 + j;
    w2f[idx] = h;
    w2f[2048 + idx] = l;
  }
}

// z split. MERGED: 128B rows [d0-15 hi|d0-15 lo|d16-31 hi|d16-31 lo] -> BOTH A0,B0.
// else: A0 = dynamic 64B rows [hi16|lo16], B0 = static 64B rows [hi16|lo16].
template<int MERGED>
__global__ void prep_z(const float* __restrict__ z, u16* __restrict__ A0, u16* __restrict__ B0) {
  int t = blockIdx.x * 256 + threadIdx.x;
  if (t >= NROWS * 8) return;
  size_t row = (size_t)(t >> 3);
  int q = t & 7;
  float4 v = *(const float4*)&z[row * 32 + q * 4];
  u16 h0 = f2bf(v.x), h1 = f2bf(v.y), h2 = f2bf(v.z), h3 = f2bf(v.w);
  u16 l0 = f2bf(v.x - bf2f(h0)), l1 = f2bf(v.y - bf2f(h1));
  u16 l2 = f2bf(v.z - bf2f(h2)), l3 = f2bf(v.w - bf2f(h3));
  u16x4 hh = {h0, h1, h2, h3};
  u16x4 ll = {l0, l1, l2, l3};
  int dd = (q & 3) * 4;
  if (MERGED) {
    int reg = (q < 4) ? 0 : 32;
    *(u16x4*)&A0[row * 64 + reg + dd] = hh;
    *(u16x4*)&A0[row * 64 + reg + 16 + dd] = ll;
    *(u16x4*)&B0[row * 64 + reg + dd] = hh;
    *(u16x4*)&B0[row * 64 + reg + 16 + dd] = ll;
  } else {
    u16* buf = (q < 4) ? A0 : B0;
    *(u16x4*)&buf[row * 32 + dd] = hh;
    *(u16x4*)&buf[row * 32 + 16 + dd] = ll;
  }
}

// ---------------- one solver step: round-4 memory shape, 5 blocks/CU ----------------
template<int FIRST, int LAST, int MERGED>
__global__ __launch_bounds__(256, 5) void step_kernel(
    const u16* __restrict__ Zin, u16* __restrict__ Zout,
    const u16* __restrict__ Sst,
    const float* __restrict__ zold, float* __restrict__ zf,
    const int* __restrict__ nl, const float* __restrict__ b1,
    const float* __restrict__ b2, const u16* __restrict__ wf,
    const u16* __restrict__ w2f) {
  // single-buffered A/h tile, fragment order [kg(16)][row(64)][j(8)]  = 32 KB total
  __shared__ __align__(16) u16 AH[16 * 64 * 8];   // 16 KB
  __shared__ __align__(16) u16 AL[16 * 64 * 8];   // 16 KB

  const int tid = threadIdx.x;
  const int lane = tid & 63;
  const int w = tid >> 6;
  const int li = lane & 15;
  const int lg = lane >> 4;

  // W1 fragments resident in registers: wave w owns cols [32w, 32w+32)
  bf16x8 WH[2][4], WL[2][4];
  #pragma unroll
  for (int nt = 0; nt < 2; ++nt)
    #pragma unroll
    for (int kt = 0; kt < 4; ++kt) {
      int kg = kt * 4 + lg;
      int n = w * 32 + nt * 16 + li;
      WH[nt][kt] = *(const bf16x8*)&wf[(kg * 128 + n) * 8];
      WL[nt][kt] = *(const bf16x8*)&wf[16384 + (kg * 128 + n) * 8];
    }
  // W2 fragments in registers (tiny, L2-hot)
  bf16x8 w2h[4], w2l[4];
  #pragma unroll
  for (int kt = 0; kt < 4; ++kt) {
    int o = ((kt * 4 + lg) * 16 + li) * 8;
    w2h[kt] = *(const bf16x8*)&w2f[o];
    w2l[kt] = *(const bf16x8*)&w2f[2048 + o];
  }

  float b1v[2][4];
  #pragma unroll
  for (int nt = 0; nt < 2; ++nt)
    #pragma unroll
    for (int r = 0; r < 4; ++r)
      b1v[nt][r] = b1[w * 32 + nt * 16 + lg * 4 + r];
  float b2v = b2[li];

  // per-lane nl index for chunk CN (w>0 only): 1 VMEM load
  #define NVLOAD(CN) nl[(((CN) * CHUNK - ((CN) / CPB) * NPATCH) + lane) * 3 + (w - 1)]

  // issue 8 GLDs for chunk CN (wave w = source section kt=w, lane = row)
  #define STAGE(CN, NV) do {                                               \
    int b_ = (CN) / CPB;                                                   \
    int pb_ = (CN) * CHUNK - b_ * NPATCH;                                  \
    int ps_ = w ? (NV) : (pb_ + lane);                                     \
    size_t r_ = (size_t)b_ * NPATCH + (size_t)ps_;                         \
    u16* ah_ = &AH[(w * 4) * 512];                                         \
    u16* al_ = &AL[(w * 4) * 512];                                         \
    if (MERGED) {                                                          \
      const u16* s_ = Zin + r_ * 64;                                       \
      GLD(s_ + 0,  ah_ + 0);    GLD(s_ + 8,  ah_ + 512);                   \
      GLD(s_ + 32, ah_ + 1024); GLD(s_ + 40, ah_ + 1536);                  \
      GLD(s_ + 16, al_ + 0);    GLD(s_ + 24, al_ + 512);                   \
      GLD(s_ + 48, al_ + 1024); GLD(s_ + 56, al_ + 1536);                  \
    } else {                                                               \
      const u16* d_ = Zin + r_ * 32;                                       \
      const u16* t_ = Sst + r_ * 32;                                       \
      GLD(d_ + 0,  ah_ + 0);    GLD(d_ + 8,  ah_ + 512);                   \
      GLD(t_ + 0,  ah_ + 1024); GLD(t_ + 8,  ah_ + 1536);                  \
      GLD(d_ + 16, al_ + 0);    GLD(d_ + 24, al_ + 512);                   \
      GLD(t_ + 16, al_ + 1024); GLD(t_ + 24, al_ + 1536);                  \
    }                                                                      \
  } while (0)

  // ---- prologue: nl for first chunk ----
  int c0 = blockIdx.x;
  int nv = 0;
  if (w) nv = NVLOAD(c0);

  for (int c = c0; c < NCHUNK; c += GRID) {
    // stage CURRENT chunk (compiler waits on nv dependency automatically)
    STAGE(c, nv);
    // prefetch nl for next chunk (1 load, left in flight across the barrier)
    {
      int cn = c + GRID; if (cn > NCHUNK - 1) cn = NCHUNK - 1;
      if (w) nv = NVLOAD(cn);
    }
    // retire this chunk's 8 GLDs; keep the nl prefetch outstanding
    if (w) { asm volatile("s_waitcnt vmcnt(1)" ::: "memory"); }
    else   { asm volatile("s_waitcnt vmcnt(0)" ::: "memory"); }
    SCHED0(); SBAR(); SCHED0();

    // ---- GEMM1 (transposed): D[n][m] = W1^T @ A^T, bf16x3 split ----
    f32x4 acc[2][4];
    #pragma unroll
    for (int nt = 0; nt < 2; ++nt)
      #pragma unroll
      for (int mt = 0; mt < 4; ++mt)
        acc[nt][mt] = (f32x4){0.f, 0.f, 0.f, 0.f};

    #pragma unroll
    for (int kt = 0; kt < 4; ++kt) {
      #pragma unroll
      for (int mt = 0; mt < 4; ++mt) {
        int off = ((kt * 4 + lg) * 64 + mt * 16 + li) * 8;
        bf16x8 ah = *(const bf16x8*)&AH[off];
        bf16x8 al = *(const bf16x8*)&AL[off];
        #pragma unroll
        for (int nt = 0; nt < 2; ++nt) {
          acc[nt][mt] = __builtin_amdgcn_mfma_f32_16x16x32_bf16(WH[nt][kt], ah, acc[nt][mt], 0, 0, 0);
          acc[nt][mt] = __builtin_amdgcn_mfma_f32_16x16x32_bf16(WH[nt][kt], al, acc[nt][mt], 0, 0, 0);
          acc[nt][mt] = __builtin_amdgcn_mfma_f32_16x16x32_bf16(WL[nt][kt], ah, acc[nt][mt], 0, 0, 0);
        }
      }
    }
    SCHED0(); SBAR(); SCHED0();   // all A reads done before h overwrites

    // ---- bias + tanh + split -> h fragments (overwrite AH/AL) ----
    #pragma unroll
    for (int nt = 0; nt < 2; ++nt) {
      #pragma unroll
      for (int mt = 0; mt < 4; ++mt) {
        u16 hh[4], ll[4];
        #pragma unroll
        for (int r = 0; r < 4; ++r) {
          float hval = acc[nt][mt][r] + b1v[nt][r];
          float e = __expf(2.0f * hval);
          float t = 1.0f - 2.0f * __builtin_amdgcn_rcpf(e + 1.0f);
          hh[r] = f2bf(t);
          ll[r] = f2bf(t - bf2f(hh[r]));
        }
        // n = w*32+nt*16+lg*4+r -> [kg2=n>>3][row=m][j=n&7]
        int base = ((w * 4 + nt * 2 + (lg >> 1)) * 64 + mt * 16 + li) * 8 + (lg & 1) * 4;
        u16x4 hv = {hh[0], hh[1], hh[2], hh[3]};
        u16x4 lv = {ll[0], ll[1], ll[2], ll[3]};
        *(u16x4*)&AH[base] = hv;
        *(u16x4*)&AL[base] = lv;
      }
    }
    asm volatile("s_waitcnt lgkmcnt(0)" ::: "memory");  // h writes retired
    SCHED0(); SBAR(); SCHED0();

    // ---- GEMM2: F[m][o] = h @ W2, bf16x3 split; wave w owns rows [16w,16w+16) ----
    f32x4 acc2 = (f32x4){0.f, 0.f, 0.f, 0.f};
    #pragma unroll
    for (int kt = 0; kt < 4; ++kt) {
      int off = ((kt * 4 + lg) * 64 + w * 16 + li) * 8;
      bf16x8 hh = *(const bf16x8*)&AH[off];
      bf16x8 hl = *(const bf16x8*)&AL[off];
      acc2 = __builtin_amdgcn_mfma_f32_16x16x32_bf16(hh, w2h[kt], acc2, 0, 0, 0);
      acc2 = __builtin_amdgcn_mfma_f32_16x16x32_bf16(hl, w2h[kt], acc2, 0, 0, 0);
      acc2 = __builtin_amdgcn_mfma_f32_16x16x32_bf16(hh, w2l[kt], acc2, 0, 0, 0);
    }

    // ---- epilogue: z_out[:, :16] = z_in[:, :16] + F (coalesced 64B per 16 lanes) ----
    #pragma unroll
    for (int r = 0; r < 4; ++r) {
      int rowg = c * CHUNK + w * 16 + lg * 4 + r;
      float F = acc2[r] + b2v;
      float zi = FIRST ? zold[(size_t)rowg * 32 + li] : zf[(size_t)rowg * 32 + li];
      float v = zi + F;
      zf[(size_t)rowg * 32 + li] = v;
      if (LAST) {
        zf[(size_t)rowg * 32 + 16 + li] = zold[(size_t)rowg * 32 + 16 + li];
      } else {
        u16 h = f2bf(v);
        u16 l = f2bf(v - bf2f(h));
        if (MERGED) {
          Zout[(size_t)rowg * 64 + li] = h;
          Zout[(size_t)rowg * 64 + 16 + li] = l;
        } else {
          Zout[(size_t)rowg * 32 + li] = h;
          Zout[(size_t)rowg * 32 + 16 + li] = l;
        }
      }
    }
    SCHED0(); SBAR(); SCHED0();   // h reads done before next chunk's STAGE overwrites
  }
  #undef STAGE
  #undef NVLOAD
}

extern "C" void kernel_launch(void* const* d_in, const int* in_sizes, int n_in,
                              void* d_out, int out_size, void* d_ws, size_t ws_size,
                              hipStream_t stream) {
  const float* z_old = (const float*)d_in[0];
  const int* nl = (const int*)d_in[1];
  const float* W1 = (const float*)d_in[2];
  const float* b1 = (const float*)d_in[3];
  const float* W2 = (const float*)d_in[4];
  const float* b2 = (const float*)d_in[5];
  float* out = (float*)d_out;

  const size_t wOff = 73728;
  const size_t DbM = (size_t)NROWS * 64 * sizeof(u16);   // 40 MB merged buffer
  const size_t DbS = (size_t)NROWS * 32 * sizeof(u16);   // 20 MB split buffer
  const size_t needM = wOff + 2 * DbM;                   // ~84 MB
  u16* wf = (u16*)d_ws;
  u16* w2f = wf + 32768;
  char* base = (char*)d_ws + wOff;

  prep_w<<<72, 256, 0, stream>>>(W1, W2, wf, w2f);

  if (ws_size >= needM) {
    u16* ZA = (u16*)base;
    u16* ZB = (u16*)(base + DbM);
    prep_z<1><<<(NROWS * 8) / 256, 256, 0, stream>>>(z_old, ZA, ZB);
    step_kernel<1, 0, 1><<<GRID, 256, 0, stream>>>(ZA, ZB, nullptr, z_old, out, nl, b1, b2, wf, w2f);
    step_kernel<0, 0, 1><<<GRID, 256, 0, stream>>>(ZB, ZA, nullptr, z_old, out, nl, b1, b2, wf, w2f);
    step_kernel<0, 0, 1><<<GRID, 256, 0, stream>>>(ZA, ZB, nullptr, z_old, out, nl, b1, b2, wf, w2f);
    step_kernel<0, 1, 1><<<GRID, 256, 0, stream>>>(ZB, ZA, nullptr, z_old, out, nl, b1, b2, wf, w2f);
  } else {
    u16* S  = (u16*)base;
    u16* DA = (u16*)(base + DbS);
    u16* DB = (u16*)(base + 2 * DbS);
    prep_z<0><<<(NROWS * 8) / 256, 256, 0, stream>>>(z_old, DA, S);
    step_kernel<1, 0, 0><<<GRID, 256, 0, stream>>>(DA, DB, S, z_old, out, nl, b1, b2, wf, w2f);
    step_kernel<0, 0, 0><<<GRID, 256, 0, stream>>>(DB, DA, S, z_old, out, nl, b1, b2, wf, w2f);
    step_kernel<0, 0, 0><<<GRID, 256, 0, stream>>>(DA, DB, S, z_old, out, nl, b1, b2, wf, w2f);
    step_kernel<0, 1, 0><<<GRID, 256, 0, stream>>>(DB, DA, S, z_old, out, nl, b1, b2, wf, w2f);
  }
}

// Round 7
// 435.927 us; speedup vs baseline: 1.7787x; 1.5809x over previous
//
#include <hip/hip_runtime.h>
#include <hip/hip_bf16.h>

typedef unsigned short u16;
typedef unsigned int u32;
typedef __attribute__((ext_vector_type(8))) short bf16x8;
typedef __attribute__((ext_vector_type(4))) float f32x4;
typedef __attribute__((ext_vector_type(4))) u16 u16x4;

#define NPATCH 81920
#define NBATCH 4
#define NROWS (NBATCH * NPATCH)   // 327680
#define HID 128
#define CHUNK 64
#define NCHUNK (NROWS / CHUNK)    // 5120
#define CPB (NPATCH / CHUNK)      // 1280
#define GRID 1024                 // 4 blocks/CU * 256 CUs; 5 chunks/block exactly

// ---------- conversion helpers (RNE) ----------
__device__ __forceinline__ u16 f2bf(float x) {
  union { __hip_bfloat16 b; u16 u; } c; c.b = __float2bfloat16(x); return c.u;
}
__device__ __forceinline__ float bf2f(u16 h) {
  union { __hip_bfloat16 b; u16 u; } c; c.u = h; return __bfloat162float(c.b);
}

// async global->LDS DMA, 16B/lane, dest = wave-uniform base + lane*16
#define GLD(g, l) __builtin_amdgcn_global_load_lds( \
    (const __attribute__((address_space(1))) void*)(g), \
    (__attribute__((address_space(3))) void*)(l), 16, 0, 0)
#define SBAR() __builtin_amdgcn_s_barrier()
#define SCHED0() __builtin_amdgcn_sched_barrier(0)

// ---------------- weight prep (layouts identical to rounds 3-6, verified) ----------------
// wf  : [part(2)][kg(16)][n(128)][j(8)]  (k' = kg*8+j = s*32+d -> W1 row d*4+s)
// w2f : [part(2)][kt(4)][lg(4)][o(16)][j(8)]
__global__ void prep_w(const float* __restrict__ W1, const float* __restrict__ W2,
                       u16* __restrict__ wf, u16* __restrict__ w2f) {
  int t = blockIdx.x * 256 + threadIdx.x;
  if (t < 128 * 128) {
    int kp = t >> 7, n = t & 127;
    int s = kp >> 5, d = kp & 31;
    float v = W1[(d * 4 + s) * HID + n];
    u16 h = f2bf(v);
    u16 l = f2bf(v - bf2f(h));
    int kg = kp >> 3, j = kp & 7;
    int o = (kg * 128 + n) * 8 + j;
    wf[o] = h;
    wf[16384 + o] = l;
  } else if (t < 128 * 128 + 2048) {
    int u = t - 128 * 128;            // u = k*16 + o
    int k = u >> 4, o = u & 15;
    float v = W2[k * 16 + o];
    u16 h = f2bf(v);
    u16 l = f2bf(v - bf2f(h));
    int kt = k >> 5, lg = (k >> 3) & 3, j = k & 7;
    int idx = ((kt * 4 + lg) * 16 + o) * 8 + j;
    w2f[idx] = h;
    w2f[2048 + idx] = l;
  }
}

// z split. MERGED: 128B rows [d0-15 hi|d0-15 lo|d16-31 hi|d16-31 lo] -> BOTH A0,B0.
// else: A0 = dynamic 64B rows [hi16|lo16], B0 = static 64B rows [hi16|lo16].
template<int MERGED>
__global__ void prep_z(const float* __restrict__ z, u16* __restrict__ A0, u16* __restrict__ B0) {
  int t = blockIdx.x * 256 + threadIdx.x;
  if (t >= NROWS * 8) return;
  size_t row = (size_t)(t >> 3);
  int q = t & 7;
  float4 v = *(const float4*)&z[row * 32 + q * 4];
  u16 h0 = f2bf(v.x), h1 = f2bf(v.y), h2 = f2bf(v.z), h3 = f2bf(v.w);
  u16 l0 = f2bf(v.x - bf2f(h0)), l1 = f2bf(v.y - bf2f(h1));
  u16 l2 = f2bf(v.z - bf2f(h2)), l3 = f2bf(v.w - bf2f(h3));
  u16x4 hh = {h0, h1, h2, h3};
  u16x4 ll = {l0, l1, l2, l3};
  int dd = (q & 3) * 4;
  if (MERGED) {
    int reg = (q < 4) ? 0 : 32;
    *(u16x4*)&A0[row * 64 + reg + dd] = hh;
    *(u16x4*)&A0[row * 64 + reg + 16 + dd] = ll;
    *(u16x4*)&B0[row * 64 + reg + dd] = hh;
    *(u16x4*)&B0[row * 64 + reg + 16 + dd] = ll;
  } else {
    u16* buf = (q < 4) ? A0 : B0;
    *(u16x4*)&buf[row * 32 + dd] = hh;
    *(u16x4*)&buf[row * 32 + 16 + dd] = ll;
  }
}

// ---------------- one solver step: round-4 memory shape, 4 blocks/CU ----------------
template<int FIRST, int LAST, int MERGED>
__global__ __launch_bounds__(256, 4) void step_kernel(
    const u16* __restrict__ Zin, u16* __restrict__ Zout,
    const u16* __restrict__ Sst,
    const float* __restrict__ zold, float* __restrict__ zf,
    const int* __restrict__ nl, const float* __restrict__ b1,
    const float* __restrict__ b2, const u16* __restrict__ wf,
    const u16* __restrict__ w2f) {
  // single-buffered A/h tile, fragment order [kg(16)][row(64)][j(8)] + W2 tiles = 40 KB
  __shared__ __align__(16) u16 AH[16 * 64 * 8];   // 16 KB
  __shared__ __align__(16) u16 AL[16 * 64 * 8];   // 16 KB
  __shared__ __align__(16) u16 W2H[2048];         // 4 KB  [kt][lg][o(16)][j]
  __shared__ __align__(16) u16 W2L[2048];         // 4 KB

  const int tid = threadIdx.x;
  const int lane = tid & 63;
  const int w = tid >> 6;
  const int li = lane & 15;
  const int lg = lane >> 4;

  // stage W2 fragments into LDS (512 slot copies of 8 elems)
  #pragma unroll
  for (int c = 0; c < 2; ++c) {
    int idx = tid + c * 256;             // 0..511
    int part = idx >> 8, slot = idx & 255;
    u16* dst = part ? W2L : W2H;
    *(bf16x8*)&dst[slot * 8] = *(const bf16x8*)&w2f[part * 2048 + slot * 8];
  }
  asm volatile("s_waitcnt lgkmcnt(0)" ::: "memory");  // W2 ds_writes retired
  // (cross-wave visibility guaranteed by the first in-loop SBAR)

  // W1 fragments resident in registers: wave w owns cols [32w, 32w+32)  (64 VGPR)
  bf16x8 WH[2][4], WL[2][4];
  #pragma unroll
  for (int nt = 0; nt < 2; ++nt)
    #pragma unroll
    for (int kt = 0; kt < 4; ++kt) {
      int kg = kt * 4 + lg;
      int n = w * 32 + nt * 16 + li;
      WH[nt][kt] = *(const bf16x8*)&wf[(kg * 128 + n) * 8];
      WL[nt][kt] = *(const bf16x8*)&wf[16384 + (kg * 128 + n) * 8];
    }

  float b1v[2][4];
  #pragma unroll
  for (int nt = 0; nt < 2; ++nt)
    #pragma unroll
    for (int r = 0; r < 4; ++r)
      b1v[nt][r] = b1[w * 32 + nt * 16 + lg * 4 + r];
  float b2v = b2[li];

  // per-lane nl index for chunk CN (w>0 only): 1 VMEM load
  #define NVLOAD(CN) nl[(((CN) * CHUNK - ((CN) / CPB) * NPATCH) + lane) * 3 + (w - 1)]

  // issue 8 GLDs for chunk CN (wave w = source section kt=w, lane = row)
  #define STAGE(CN, NV) do {                                               \
    int b_ = (CN) / CPB;                                                   \
    int pb_ = (CN) * CHUNK - b_ * NPATCH;                                  \
    int ps_ = w ? (NV) : (pb_ + lane);                                     \
    size_t r_ = (size_t)b_ * NPATCH + (size_t)ps_;                         \
    u16* ah_ = &AH[(w * 4) * 512];                                         \
    u16* al_ = &AL[(w * 4) * 512];                                         \
    if (MERGED) {                                                          \
      const u16* s_ = Zin + r_ * 64;                                       \
      GLD(s_ + 0,  ah_ + 0);    GLD(s_ + 8,  ah_ + 512);                   \
      GLD(s_ + 32, ah_ + 1024); GLD(s_ + 40, ah_ + 1536);                  \
      GLD(s_ + 16, al_ + 0);    GLD(s_ + 24, al_ + 512);                   \
      GLD(s_ + 48, al_ + 1024); GLD(s_ + 56, al_ + 1536);                  \
    } else {                                                               \
      const u16* d_ = Zin + r_ * 32;                                       \
      const u16* t_ = Sst + r_ * 32;                                       \
      GLD(d_ + 0,  ah_ + 0);    GLD(d_ + 8,  ah_ + 512);                   \
      GLD(t_ + 0,  ah_ + 1024); GLD(t_ + 8,  ah_ + 1536);                  \
      GLD(d_ + 16, al_ + 0);    GLD(d_ + 24, al_ + 512);                   \
      GLD(t_ + 16, al_ + 1024); GLD(t_ + 24, al_ + 1536);                  \
    }                                                                      \
  } while (0)

  // ---- prologue: nl for first chunk ----
  int c0 = blockIdx.x;
  int nv = 0;
  if (w) nv = NVLOAD(c0);

  for (int c = c0; c < NCHUNK; c += GRID) {
    // stage CURRENT chunk (compiler waits on nv dependency automatically)
    STAGE(c, nv);
    // prefetch nl for next chunk (1 load, left in flight across the barrier)
    {
      int cn = c + GRID; if (cn > NCHUNK - 1) cn = NCHUNK - 1;
      if (w) nv = NVLOAD(cn);
    }
    // retire this chunk's 8 GLDs; keep the nl prefetch outstanding
    if (w) { asm volatile("s_waitcnt vmcnt(1)" ::: "memory"); }
    else   { asm volatile("s_waitcnt vmcnt(0)" ::: "memory"); }
    SCHED0(); SBAR(); SCHED0();

    // ---- GEMM1 (transposed): D[n][m] = W1^T @ A^T, bf16x3 split ----
    f32x4 acc[2][4];
    #pragma unroll
    for (int nt = 0; nt < 2; ++nt)
      #pragma unroll
      for (int mt = 0; mt < 4; ++mt)
        acc[nt][mt] = (f32x4){0.f, 0.f, 0.f, 0.f};

    #pragma unroll
    for (int kt = 0; kt < 4; ++kt) {
      #pragma unroll
      for (int mt = 0; mt < 4; ++mt) {
        int off = ((kt * 4 + lg) * 64 + mt * 16 + li) * 8;
        bf16x8 ah = *(const bf16x8*)&AH[off];
        bf16x8 al = *(const bf16x8*)&AL[off];
        #pragma unroll
        for (int nt = 0; nt < 2; ++nt) {
          acc[nt][mt] = __builtin_amdgcn_mfma_f32_16x16x32_bf16(WH[nt][kt], ah, acc[nt][mt], 0, 0, 0);
          acc[nt][mt] = __builtin_amdgcn_mfma_f32_16x16x32_bf16(WH[nt][kt], al, acc[nt][mt], 0, 0, 0);
          acc[nt][mt] = __builtin_amdgcn_mfma_f32_16x16x32_bf16(WL[nt][kt], ah, acc[nt][mt], 0, 0, 0);
        }
      }
    }
    SCHED0(); SBAR(); SCHED0();   // all A reads done before h overwrites

    // ---- bias + tanh + split -> h fragments (overwrite AH/AL) ----
    #pragma unroll
    for (int nt = 0; nt < 2; ++nt) {
      #pragma unroll
      for (int mt = 0; mt < 4; ++mt) {
        u16 hh[4], ll[4];
        #pragma unroll
        for (int r = 0; r < 4; ++r) {
          float hval = acc[nt][mt][r] + b1v[nt][r];
          float e = __expf(2.0f * hval);
          float t = 1.0f - 2.0f * __builtin_amdgcn_rcpf(e + 1.0f);
          hh[r] = f2bf(t);
          ll[r] = f2bf(t - bf2f(hh[r]));
        }
        // n = w*32+nt*16+lg*4+r -> [kg2=n>>3][row=m][j=n&7]
        int base = ((w * 4 + nt * 2 + (lg >> 1)) * 64 + mt * 16 + li) * 8 + (lg & 1) * 4;
        u16x4 hv = {hh[0], hh[1], hh[2], hh[3]};
        u16x4 lv = {ll[0], ll[1], ll[2], ll[3]};
        *(u16x4*)&AH[base] = hv;
        *(u16x4*)&AL[base] = lv;
      }
    }
    asm volatile("s_waitcnt lgkmcnt(0)" ::: "memory");  // h writes retired
    SCHED0(); SBAR(); SCHED0();

    // ---- GEMM2: F[m][o] = h @ W2, bf16x3 split; wave w owns rows [16w,16w+16) ----
    f32x4 acc2 = (f32x4){0.f, 0.f, 0.f, 0.f};
    #pragma unroll
    for (int kt = 0; kt < 4; ++kt) {
      int woff = ((kt * 4 + lg) * 16 + li) * 8;
      bf16x8 wh = *(const bf16x8*)&W2H[woff];
      bf16x8 wl = *(const bf16x8*)&W2L[woff];
      int off = ((kt * 4 + lg) * 64 + w * 16 + li) * 8;
      bf16x8 hh = *(const bf16x8*)&AH[off];
      bf16x8 hl = *(const bf16x8*)&AL[off];
      acc2 = __builtin_amdgcn_mfma_f32_16x16x32_bf16(hh, wh, acc2, 0, 0, 0);
      acc2 = __builtin_amdgcn_mfma_f32_16x16x32_bf16(hl, wh, acc2, 0, 0, 0);
      acc2 = __builtin_amdgcn_mfma_f32_16x16x32_bf16(hh, wl, acc2, 0, 0, 0);
    }

    // ---- epilogue: z_out[:, :16] = z_in[:, :16] + F (coalesced 64B per 16 lanes) ----
    #pragma unroll
    for (int r = 0; r < 4; ++r) {
      int rowg = c * CHUNK + w * 16 + lg * 4 + r;
      float F = acc2[r] + b2v;
      float zi = FIRST ? zold[(size_t)rowg * 32 + li] : zf[(size_t)rowg * 32 + li];
      float v = zi + F;
      zf[(size_t)rowg * 32 + li] = v;
      if (LAST) {
        zf[(size_t)rowg * 32 + 16 + li] = zold[(size_t)rowg * 32 + 16 + li];
      } else {
        u16 h = f2bf(v);
        u16 l = f2bf(v - bf2f(h));
        if (MERGED) {
          Zout[(size_t)rowg * 64 + li] = h;
          Zout[(size_t)rowg * 64 + 16 + li] = l;
        } else {
          Zout[(size_t)rowg * 32 + li] = h;
          Zout[(size_t)rowg * 32 + 16 + li] = l;
        }
      }
    }
    SCHED0(); SBAR(); SCHED0();   // h reads done before next chunk's STAGE overwrites
  }
  #undef STAGE
  #undef NVLOAD
}

extern "C" void kernel_launch(void* const* d_in, const int* in_sizes, int n_in,
                              void* d_out, int out_size, void* d_ws, size_t ws_size,
                              hipStream_t stream) {
  const float* z_old = (const float*)d_in[0];
  const int* nl = (const int*)d_in[1];
  const float* W1 = (const float*)d_in[2];
  const float* b1 = (const float*)d_in[3];
  const float* W2 = (const float*)d_in[4];
  const float* b2 = (const float*)d_in[5];
  float* out = (float*)d_out;

  const size_t wOff = 73728;
  const size_t DbM = (size_t)NROWS * 64 * sizeof(u16);   // 40 MB merged buffer
  const size_t DbS = (size_t)NROWS * 32 * sizeof(u16);   // 20 MB split buffer
  const size_t needM = wOff + 2 * DbM;                   // ~84 MB
  u16* wf = (u16*)d_ws;
  u16* w2f = wf + 32768;
  char* base = (char*)d_ws + wOff;

  prep_w<<<72, 256, 0, stream>>>(W1, W2, wf, w2f);

  if (ws_size >= needM) {
    u16* ZA = (u16*)base;
    u16* ZB = (u16*)(base + DbM);
    prep_z<1><<<(NROWS * 8) / 256, 256, 0, stream>>>(z_old, ZA, ZB);
    step_kernel<1, 0, 1><<<GRID, 256, 0, stream>>>(ZA, ZB, nullptr, z_old, out, nl, b1, b2, wf, w2f);
    step_kernel<0, 0, 1><<<GRID, 256, 0, stream>>>(ZB, ZA, nullptr, z_old, out, nl, b1, b2, wf, w2f);
    step_kernel<0, 0, 1><<<GRID, 256, 0, stream>>>(ZA, ZB, nullptr, z_old, out, nl, b1, b2, wf, w2f);
    step_kernel<0, 1, 1><<<GRID, 256, 0, stream>>>(ZB, ZA, nullptr, z_old, out, nl, b1, b2, wf, w2f);
  } else {
    u16* S  = (u16*)base;
    u16* DA = (u16*)(base + DbS);
    u16* DB = (u16*)(base + 2 * DbS);
    prep_z<0><<<(NROWS * 8) / 256, 256, 0, stream>>>(z_old, DA, S);
    step_kernel<1, 0, 0><<<GRID, 256, 0, stream>>>(DA, DB, S, z_old, out, nl, b1, b2, wf, w2f);
    step_kernel<0, 0, 0><<<GRID, 256, 0, stream>>>(DB, DA, S, z_old, out, nl, b1, b2, wf, w2f);
    step_kernel<0, 0, 0><<<GRID, 256, 0, stream>>>(DA, DB, S, z_old, out, nl, b1, b2, wf, w2f);
    step_kernel<0, 1, 0><<<GRID, 256, 0, stream>>>(DB, DA, S, z_old, out, nl, b1, b2, wf, w2f);
  }
}